// Round 6
// baseline (1221.767 us; speedup 1.0000x reference)
//
#include <hip/hip_runtime.h>

#define DEVINL static __device__ __forceinline__

DEVINL float tanh_fast(float x) {
  // tanh(x) = 1 - 2/(e^{2x}+1); e+1 in [1,inf] -> never NaN
  float e = __expf(2.0f * x);
  return 1.0f - 2.0f / (e + 1.0f);
}
DEVINL float rsum32(float v) {
  // sum across each 32-lane half-wave (xor masks < 32 stay within halves)
  v += __shfl_xor(v, 16);
  v += __shfl_xor(v, 8);
  v += __shfl_xor(v, 4);
  v += __shfl_xor(v, 2);
  v += __shfl_xor(v, 1);
  return v;
}

constexpr int TSTEPS = 256;

// wave = 2 batch elements x 32 neurons. block = 64 (1 wave), grid = 4096/2.
__global__ __launch_bounds__(64, 2) void reac_kernel(
    const float* __restrict__ useq,   // [B][T] f32
    const float* __restrict__ xz0,    // [B][26] f32
    const float* __restrict__ r1W0, const float* __restrict__ r1b0,
    const float* __restrict__ r1W1, const float* __restrict__ r1b1,
    const float* __restrict__ r1W2, const float* __restrict__ r1b2,
    const float* __restrict__ r2W0, const float* __restrict__ r2b0,
    const float* __restrict__ r2W1, const float* __restrict__ r2b1,
    const float* __restrict__ r2W2, const float* __restrict__ r2b2,
    const float* __restrict__ r3W0, const float* __restrict__ r3b0,
    const float* __restrict__ r3W1, const float* __restrict__ r3b1,
    const float* __restrict__ r3W2, const float* __restrict__ r3b2,
    float2* __restrict__ out)         // [B][T] -> (x0,x1) f32
{
  const int lane = threadIdx.x;
  const int bl = lane >> 5;     // batch slot within wave
  const int j  = lane & 31;     // neuron index
  const int b  = blockIdx.x * 2 + bl;

  // ---- per-lane weights in registers (column j of each matrix) ----
  float w0A = r1W0[j], b0A = r1b0[j];
  float w0B = r2W0[j], b0B = r2b0[j];
  float b1A = r1b1[j], b1B = r2b1[j];
  float w2A = r1W2[j], w2B = r2W2[j];
  float b2A = r1b2[0], b2B = r2b2[0];
  float b0C = r3b0[j], b1C = r3b1[j];
  float w2C = r3W2[j], b2C = r3b2[0];

  float W1A[32], W1B[32], W1C[32], W0C[24];
#pragma unroll
  for (int k = 0; k < 32; ++k) {
    W1A[k] = r1W1[k * 32 + j];
    W1B[k] = r2W1[k * 32 + j];
    W1C[k] = r3W1[k * 32 + j];
  }
#pragma unroll
  for (int k = 0; k < 24; ++k) W0C[k] = r3W0[k * 32 + j];

  __shared__ __align__(16) float zs[2][24];  // z state
  __shared__ __align__(16) float zb[2][24];  // z23 / z4 buffer
  __shared__ __align__(16) float hA[2][32];  // h1 broadcast r1
  __shared__ __align__(16) float hB[2][32];  // h1 broadcast r2
  __shared__ __align__(16) float hC[2][32];  // h1 broadcast r3

  float x0 = xz0[b * 26 + 0];
  float x1 = xz0[b * 26 + 1];
  if (j < 24) zs[bl][j] = xz0[b * 26 + 2 + j];
  __syncthreads();

  // r3 MLP on a z row sitting in LDS (uniform broadcast reads)
  auto eval_r3 = [&](const float* zrow) -> float {
    const float4* zp = (const float4*)zrow;
    float acc = b0C;
#pragma unroll
    for (int q = 0; q < 6; ++q) {
      float4 zz = zp[q];
      acc = fmaf(zz.x, W0C[4 * q + 0], acc);
      acc = fmaf(zz.y, W0C[4 * q + 1], acc);
      acc = fmaf(zz.z, W0C[4 * q + 2], acc);
      acc = fmaf(zz.w, W0C[4 * q + 3], acc);
    }
    float h1 = tanh_fast(acc);
    __syncthreads();                 // WAR vs previous hC readers
    hC[bl][j] = h1;
    __syncthreads();
    const float4* hp = (const float4*)&hC[bl][0];
    float a2 = b1C;
#pragma unroll
    for (int q = 0; q < 8; ++q) {
      float4 hh = hp[q];
      a2 = fmaf(hh.x, W1C[4 * q + 0], a2);
      a2 = fmaf(hh.y, W1C[4 * q + 1], a2);
      a2 = fmaf(hh.z, W1C[4 * q + 2], a2);
      a2 = fmaf(hh.w, W1C[4 * q + 3], a2);
    }
    float h2 = tanh_fast(a2);
    return (rsum32(h2 * w2C) + b2C) * 0.2f;   // * Cbstd
  };

  // fused r1(s0) and r2(s1)
  auto eval_r12 = [&](float s0, float s1, float& ra, float& rb) {
    float h1a = tanh_fast(fmaf(s0, w0A, b0A));
    float h1b = tanh_fast(fmaf(s1, w0B, b0B));
    __syncthreads();                 // WAR vs previous hA/hB readers
    hA[bl][j] = h1a;
    hB[bl][j] = h1b;
    __syncthreads();
    const float4* pa = (const float4*)&hA[bl][0];
    const float4* pb = (const float4*)&hB[bl][0];
    float aA = b1A, aB = b1B;
#pragma unroll
    for (int q = 0; q < 8; ++q) {
      float4 va = pa[q];
      float4 vb = pb[q];
      aA = fmaf(va.x, W1A[4 * q + 0], aA);
      aA = fmaf(va.y, W1A[4 * q + 1], aA);
      aA = fmaf(va.z, W1A[4 * q + 2], aA);
      aA = fmaf(va.w, W1A[4 * q + 3], aA);
      aB = fmaf(vb.x, W1B[4 * q + 0], aB);
      aB = fmaf(vb.y, W1B[4 * q + 1], aB);
      aB = fmaf(vb.z, W1B[4 * q + 2], aB);
      aB = fmaf(vb.w, W1B[4 * q + 3], aB);
    }
    float h2a = tanh_fast(aA);
    float h2b = tanh_fast(aB);
    ra = (rsum32(h2a * w2A) + b2A) * 0.3f;   // * Castd
    rb = (rsum32(h2b * w2B) + b2B) * 0.2f;   // * Cbstd
  };

  auto mixk = [&](float sx0, float sx1, float Caf, float ra, float rb, float rc,
                  float& kx, float& ky) {
    float Ca = fmaf(sx0, 0.3f, 0.5f);
    float Cb = fmaf(sx1, 0.2f, 0.5f);
    float dCa = 0.1f * (Caf - Ca) - ra;
    float dCb = fmaf(-0.1f, Cb, ra - 3.0f * rb + rc);
    kx = dCa * (1.0f / 0.3f);
    ky = dCb * (1.0f / 0.2f);
  };

  for (int t = 0; t < TSTEPS; ++t) {
    float u = useq[b * TSTEPS + t];
    float Caf = fmaf(u, 0.5f, 1.0f);

    // emit y_t = x (pre-update), two f32s
    if (j == 0) {
      out[b * TSTEPS + t] = make_float2(x0, x1);
    }

    // ---- stage 1: r3 on current z ----
    float rc1 = eval_r3(&zs[bl][0]);

    // build z23 = [interp(concat(xpseq,x)), upseq] into zb
    __syncthreads();                 // WAR vs prev step's zb readers
    if (j < 16) {
      float yn = (j < 14) ? zs[bl][j + 2] : ((j == 14) ? x0 : x1);
      zb[bl][j] = 0.5f * (zs[bl][j] + yn);
    } else if (j < 24) {
      zb[bl][j] = zs[bl][j];         // upseq
    }
    __syncthreads();

    float ra, rb, kx1, ky1, kx2, ky2, kx3, ky3, kx4, ky4;
    eval_r12(x0, x1, ra, rb);
    mixk(x0, x1, Caf, ra, rb, rc1, kx1, ky1);

    float rc23 = eval_r3(&zb[bl][0]);   // shared by k2 and k3

    float sx = fmaf(kx1, 0.5f, x0), sy = fmaf(ky1, 0.5f, x1);
    eval_r12(sx, sy, ra, rb);
    mixk(sx, sy, Caf, ra, rb, rc23, kx2, ky2);

    sx = fmaf(kx2, 0.5f, x0); sy = fmaf(ky2, 0.5f, x1);
    eval_r12(sx, sy, ra, rb);
    mixk(sx, sy, Caf, ra, rb, rc23, kx3, ky3);

    // z4: first 16 entries differ from z23; [16:24] (upseq) already in zb
    __syncthreads();
    if (j < 16) {
      zb[bl][j] = (j < 14) ? zs[bl][j + 2] : ((j == 14) ? x0 : x1);
    }
    __syncthreads();

    float rc4 = eval_r3(&zb[bl][0]);

    sx = x0 + kx3; sy = x1 + ky3;
    eval_r12(sx, sy, ra, rb);
    mixk(sx, sy, Caf, ra, rb, rc4, kx4, ky4);

    // ---- state update: zplus = [z[2:16], x, up[1:], u] ----
    float znew = 0.0f;
    if (j < 24) {
      znew = (j < 14) ? zs[bl][j + 2]
           : (j == 14) ? x0
           : (j == 15) ? x1
           : (j < 23)  ? zs[bl][j + 1]
                       : u;
    }
    __syncthreads();                 // reads of zs done before overwrite
    if (j < 24) zs[bl][j] = znew;
    x0 += (kx1 + 2.0f * (kx2 + kx3) + kx4) * (1.0f / 6.0f);
    x1 += (ky1 + 2.0f * (ky2 + ky3) + ky4) * (1.0f / 6.0f);
    __syncthreads();
  }
}

extern "C" void kernel_launch(void* const* d_in, const int* in_sizes, int n_in,
                              void* d_out, int out_size, void* d_ws, size_t ws_size,
                              hipStream_t stream) {
  const float* p[20];
  for (int i = 0; i < 20; ++i) p[i] = (const float*)d_in[i];
  reac_kernel<<<dim3(2048), dim3(64), 0, stream>>>(
      p[0], p[1], p[2], p[3], p[4], p[5], p[6], p[7], p[8], p[9], p[10],
      p[11], p[12], p[13], p[14], p[15], p[16], p[17], p[18], p[19],
      (float2*)d_out);
}

// Round 7
// 943.857 us; speedup vs baseline: 1.2944x; 1.2944x over previous
//
#include <hip/hip_runtime.h>

#define DEVINL static __device__ __forceinline__
// Single-wave workgroup: LDS ops from one wave execute in issue order, so a
// compiler fence + lgkmcnt drain replaces __syncthreads (no s_barrier, no
// vmcnt(0) drain of the output store).
#define LDSBAR() asm volatile("s_waitcnt lgkmcnt(0)" ::: "memory")

DEVINL float tanh_fast(float x) {
  // tanh(x) = 1 - 2/(e^{2x}+1); e+1 in [1,inf] -> never NaN
  float e = __expf(2.0f * x);
  return 1.0f - 2.0f * __builtin_amdgcn_rcpf(e + 1.0f);
}

template <int CTRL>
DEVINL float dpp_add(float v) {
  int t = __builtin_amdgcn_update_dpp(0, __float_as_int(v), CTRL, 0xF, 0xF, true);
  return v + __int_as_float(t);
}
// Sum across each 32-lane half-wave; result in all lanes of the half.
DEVINL float rsum32(float v) {
  v = dpp_add<0xB1>(v);    // quad_perm [1,0,3,2]  -> pair sums
  v = dpp_add<0x4E>(v);    // quad_perm [2,3,0,1]  -> quad sums
  v = dpp_add<0x141>(v);   // row_half_mirror      -> sums of 8
  v = dpp_add<0x140>(v);   // row_mirror           -> sums of 16
  v += __int_as_float(__builtin_amdgcn_ds_swizzle(__float_as_int(v), 0x401F)); // xor16
  return v;
}

DEVINL float dot4(float4 v, const float* w) {
  return fmaf(v.x, w[0], fmaf(v.y, w[1], fmaf(v.z, w[2], v.w * w[3])));
}
// 32-wide dot against an LDS row (uniform broadcast reads), 4 accumulators.
DEVINL float dot32(const float4* hp, const float* W, float bias) {
  float a0 = bias, a1 = 0.f, a2 = 0.f, a3 = 0.f;
#pragma unroll
  for (int q = 0; q < 8; q += 4) {
    float4 h0 = hp[q], h1 = hp[q + 1], h2 = hp[q + 2], h3 = hp[q + 3];
    a0 = fmaf(h0.x, W[4 * q + 0], a0);  a0 = fmaf(h0.y, W[4 * q + 1], a0);
    a0 = fmaf(h0.z, W[4 * q + 2], a0);  a0 = fmaf(h0.w, W[4 * q + 3], a0);
    a1 = fmaf(h1.x, W[4 * q + 4], a1);  a1 = fmaf(h1.y, W[4 * q + 5], a1);
    a1 = fmaf(h1.z, W[4 * q + 6], a1);  a1 = fmaf(h1.w, W[4 * q + 7], a1);
    a2 = fmaf(h2.x, W[4 * q + 8], a2);  a2 = fmaf(h2.y, W[4 * q + 9], a2);
    a2 = fmaf(h2.z, W[4 * q + 10], a2); a2 = fmaf(h2.w, W[4 * q + 11], a2);
    a3 = fmaf(h3.x, W[4 * q + 12], a3); a3 = fmaf(h3.y, W[4 * q + 13], a3);
    a3 = fmaf(h3.z, W[4 * q + 14], a3); a3 = fmaf(h3.w, W[4 * q + 15], a3);
  }
  return (a0 + a1) + (a2 + a3);
}

constexpr int TSTEPS = 256;

// wave = 2 batch elements x 32 neurons. block = 64 (1 wave), grid = 4096/2.
__global__ __launch_bounds__(64, 2) void reac_kernel(
    const float* __restrict__ useq,   // [B][T] f32
    const float* __restrict__ xz0,    // [B][26] f32
    const float* __restrict__ r1W0, const float* __restrict__ r1b0,
    const float* __restrict__ r1W1, const float* __restrict__ r1b1,
    const float* __restrict__ r1W2, const float* __restrict__ r1b2,
    const float* __restrict__ r2W0, const float* __restrict__ r2b0,
    const float* __restrict__ r2W1, const float* __restrict__ r2b1,
    const float* __restrict__ r2W2, const float* __restrict__ r2b2,
    const float* __restrict__ r3W0, const float* __restrict__ r3b0,
    const float* __restrict__ r3W1, const float* __restrict__ r3b1,
    const float* __restrict__ r3W2, const float* __restrict__ r3b2,
    float2* __restrict__ out)         // [B][T] -> (x0,x1) f32
{
  const int lane = threadIdx.x;
  const int bl = lane >> 5;     // batch slot within wave
  const int j  = lane & 31;     // neuron index
  const int b  = blockIdx.x * 2 + bl;

  // ---- per-lane weights in registers (column j of each matrix) ----
  float w0A = r1W0[j], b0A = r1b0[j];
  float w0B = r2W0[j], b0B = r2b0[j];
  float b1A = r1b1[j], b1B = r2b1[j];
  float w2A = r1W2[j], w2B = r2W2[j];
  float b2A = r1b2[0], b2B = r2b2[0];
  float b0C = r3b0[j], b1C = r3b1[j];
  float w2C = r3W2[j], b2C = r3b2[0];

  float W1A[32], W1B[32], W1C[32], W0C[24];
#pragma unroll
  for (int k = 0; k < 32; ++k) {
    W1A[k] = r1W1[k * 32 + j];
    W1B[k] = r2W1[k * 32 + j];
    W1C[k] = r3W1[k * 32 + j];
  }
#pragma unroll
  for (int k = 0; k < 24; ++k) W0C[k] = r3W0[k * 32 + j];

  __shared__ __align__(16) float zs[2][24];     // z state
  __shared__ __align__(16) float zb[2][16];     // z4 prefix (z4[0:16])
  __shared__ __align__(16) float hA[2][32];     // h1 broadcast r1
  __shared__ __align__(16) float hB[2][32];     // h1 broadcast r2
  __shared__ __align__(16) float hR3[2][3][32]; // h1 broadcast r3 (z, z23, z4)

  float x0 = xz0[b * 26 + 0];
  float x1 = xz0[b * 26 + 1];
  if (j < 24) zs[bl][j] = xz0[b * 26 + 2 + j];
  LDSBAR();

  // fused r1(s0) and r2(s1)
  auto eval_r12 = [&](float s0, float s1, float& ra, float& rb) {
    float h1a = tanh_fast(fmaf(s0, w0A, b0A));
    float h1b = tanh_fast(fmaf(s1, w0B, b0B));
    hA[bl][j] = h1a;
    hB[bl][j] = h1b;
    LDSBAR();
    float aA = dot32((const float4*)&hA[bl][0], W1A, b1A);
    float aB = dot32((const float4*)&hB[bl][0], W1B, b1B);
    ra = (rsum32(tanh_fast(aA) * w2A) + b2A) * 0.3f;   // * Castd
    rb = (rsum32(tanh_fast(aB) * w2B) + b2B) * 0.2f;   // * Cbstd
  };

  auto mixk = [&](float sx0, float sx1, float Caf, float ra, float rb, float rc,
                  float& kx, float& ky) {
    float Ca = fmaf(sx0, 0.3f, 0.5f);
    float Cb = fmaf(sx1, 0.2f, 0.5f);
    float dCa = 0.1f * (Caf - Ca) - ra;
    float dCb = fmaf(-0.1f, Cb, ra - 3.0f * rb + rc);
    kx = dCa * (1.0f / 0.3f);
    ky = dCb * (1.0f / 0.2f);
  };

  float u = useq[b * TSTEPS];

  for (int t = 0; t < TSTEPS; ++t) {
    // prefetch next u (full step to cover latency)
    int tn = (t < TSTEPS - 1) ? (t + 1) : t;
    float u_nxt = useq[b * TSTEPS + tn];
    float Caf = fmaf(u, 0.5f, 1.0f);

    // emit y_t = x (pre-update)
    if (j == 0) out[b * TSTEPS + t] = make_float2(x0, x1);

    // build z4 prefix: zb[i] = xpseq[2:],x  (z23 derived by linearity)
    if (j < 16) {
      zb[bl][j] = (j < 14) ? zs[bl][j + 2] : ((j == 14) ? x0 : x1);
    }
    LDSBAR();

    // ---- fused r3 x3 (z, z23, z4): layer 0 via linearity ----
    const float4* zsp = (const float4*)&zs[bl][0];
    const float4* zbp = (const float4*)&zb[bl][0];
    float4 za0 = zsp[0], za1 = zsp[1], za2 = zsp[2], za3 = zsp[3];
    float4 zu0 = zsp[4], zu1 = zsp[5];
    float4 q0 = zbp[0], q1 = zbp[1], q2 = zbp[2], q3 = zbp[3];
    float accS = (dot4(za0, W0C) + dot4(za1, W0C + 4)) +
                 (dot4(za2, W0C + 8) + dot4(za3, W0C + 12));
    float accB = (dot4(q0, W0C) + dot4(q1, W0C + 4)) +
                 (dot4(q2, W0C + 8) + dot4(q3, W0C + 12));
    float accU = dot4(zu0, W0C + 16) + dot4(zu1, W0C + 20) + b0C;
    float a1v = accS + accU;                      // z
    float a4v = accB + accU;                      // z4
    float a23v = fmaf(0.5f, accS + accB, accU);   // z23 = 0.5(z+z4)
    hR3[bl][0][j] = tanh_fast(a1v);
    hR3[bl][1][j] = tanh_fast(a23v);
    hR3[bl][2][j] = tanh_fast(a4v);
    LDSBAR();
    float o1 = dot32((const float4*)&hR3[bl][0][0], W1C, b1C);
    float o23 = dot32((const float4*)&hR3[bl][1][0], W1C, b1C);
    float o4 = dot32((const float4*)&hR3[bl][2][0], W1C, b1C);
    float rc1 = (rsum32(tanh_fast(o1) * w2C) + b2C) * 0.2f;
    float rc23 = (rsum32(tanh_fast(o23) * w2C) + b2C) * 0.2f;
    float rc4 = (rsum32(tanh_fast(o4) * w2C) + b2C) * 0.2f;

    // ---- RK stages (r1/r2 serial chain) ----
    float ra, rb, kx1, ky1, kx2, ky2, kx3, ky3, kx4, ky4;
    eval_r12(x0, x1, ra, rb);
    mixk(x0, x1, Caf, ra, rb, rc1, kx1, ky1);

    float sx = fmaf(kx1, 0.5f, x0), sy = fmaf(ky1, 0.5f, x1);
    eval_r12(sx, sy, ra, rb);
    mixk(sx, sy, Caf, ra, rb, rc23, kx2, ky2);

    sx = fmaf(kx2, 0.5f, x0); sy = fmaf(ky2, 0.5f, x1);
    eval_r12(sx, sy, ra, rb);
    mixk(sx, sy, Caf, ra, rb, rc23, kx3, ky3);

    sx = x0 + kx3; sy = x1 + ky3;
    eval_r12(sx, sy, ra, rb);
    mixk(sx, sy, Caf, ra, rb, rc4, kx4, ky4);

    // ---- state update: zplus = [xpseq[2:], x, upseq[1:], u] ----
    float znew = 0.0f;
    if (j < 16) znew = zb[bl][j];            // == [xpseq[2:], x]
    else if (j < 23) znew = zs[bl][j + 1];   // upseq shift
    else if (j == 23) znew = u;
    LDSBAR();                                // reads done before overwrite
    if (j < 24) zs[bl][j] = znew;
    x0 += (kx1 + 2.0f * (kx2 + kx3) + kx4) * (1.0f / 6.0f);
    x1 += (ky1 + 2.0f * (ky2 + ky3) + ky4) * (1.0f / 6.0f);
    u = u_nxt;
    LDSBAR();                                // zs visible to next iteration
  }
}

extern "C" void kernel_launch(void* const* d_in, const int* in_sizes, int n_in,
                              void* d_out, int out_size, void* d_ws, size_t ws_size,
                              hipStream_t stream) {
  const float* p[20];
  for (int i = 0; i < 20; ++i) p[i] = (const float*)d_in[i];
  reac_kernel<<<dim3(2048), dim3(64), 0, stream>>>(
      p[0], p[1], p[2], p[3], p[4], p[5], p[6], p[7], p[8], p[9], p[10],
      p[11], p[12], p[13], p[14], p[15], p[16], p[17], p[18], p[19],
      (float2*)d_out);
}

// Round 8
// 916.639 us; speedup vs baseline: 1.3329x; 1.0297x over previous
//
#include <hip/hip_runtime.h>

#define DEVINL static __device__ __forceinline__
// Single-wave workgroup: the wave's own lgkmcnt orders all its LDS ops; a
// compiler fence + lgkmcnt drain replaces __syncthreads entirely.
#define LDSBAR() asm volatile("s_waitcnt lgkmcnt(0)" ::: "memory")

DEVINL float tanh_fast(float x) {
  // tanh(x) = 1 - 2/(e^{2x}+1); e+1 in [1,inf] -> never NaN
  float e = __expf(2.0f * x);
  return 1.0f - 2.0f * __builtin_amdgcn_rcpf(e + 1.0f);
}

template <int CTRL>
DEVINL float dpp_add(float v) {
  int t = __builtin_amdgcn_update_dpp(0, __float_as_int(v), CTRL, 0xF, 0xF, true);
  return v + __int_as_float(t);
}
// Sum across each 32-lane half-wave; result replicated in all lanes of the half.
DEVINL float rsum32(float v) {
  v = dpp_add<0xB1>(v);    // quad_perm [1,0,3,2]  -> pair sums
  v = dpp_add<0x4E>(v);    // quad_perm [2,3,0,1]  -> quad sums
  v = dpp_add<0x141>(v);   // row_half_mirror      -> sums of 8
  v = dpp_add<0x140>(v);   // row_mirror           -> sums of 16
  v += __int_as_float(__builtin_amdgcn_ds_swizzle(__float_as_int(v), 0x401F)); // xor16
  return v;
}

DEVINL float dot4(float4 v, const float* w) {
  return fmaf(v.x, w[0], fmaf(v.y, w[1], fmaf(v.z, w[2], v.w * w[3])));
}
// 32-wide dot vs an LDS row (uniform address within each half), 4 accumulators.
DEVINL float dot32(const float* hrow, const float* W, float bias) {
  const float4* hp = (const float4*)hrow;
  float a0 = bias, a1 = 0.f, a2 = 0.f, a3 = 0.f;
#pragma unroll
  for (int q = 0; q < 8; q += 2) {
    float4 x = hp[q], y = hp[q + 1];
    a0 = fmaf(x.x, W[4 * q + 0], a0); a1 = fmaf(x.y, W[4 * q + 1], a1);
    a2 = fmaf(x.z, W[4 * q + 2], a2); a3 = fmaf(x.w, W[4 * q + 3], a3);
    a0 = fmaf(y.x, W[4 * q + 4], a0); a1 = fmaf(y.y, W[4 * q + 5], a1);
    a2 = fmaf(y.z, W[4 * q + 6], a2); a3 = fmaf(y.w, W[4 * q + 7], a3);
  }
  return (a0 + a1) + (a2 + a3);
}
// 16-wide partial dot (k-split r3 layer 1)
DEVINL float pdot16(const float* hrow, const float* W) {
  const float4* hp = (const float4*)hrow;
  float a0 = 0.f, a1 = 0.f, a2 = 0.f, a3 = 0.f;
  float4 x = hp[0], y = hp[1];
  a0 = fmaf(x.x, W[0], a0);  a1 = fmaf(x.y, W[1], a1);
  a2 = fmaf(x.z, W[2], a2);  a3 = fmaf(x.w, W[3], a3);
  a0 = fmaf(y.x, W[4], a0);  a1 = fmaf(y.y, W[5], a1);
  a2 = fmaf(y.z, W[6], a2);  a3 = fmaf(y.w, W[7], a3);
  x = hp[2]; y = hp[3];
  a0 = fmaf(x.x, W[8], a0);  a1 = fmaf(x.y, W[9], a1);
  a2 = fmaf(x.z, W[10], a2); a3 = fmaf(x.w, W[11], a3);
  a0 = fmaf(y.x, W[12], a0); a1 = fmaf(y.y, W[13], a1);
  a2 = fmaf(y.z, W[14], a2); a3 = fmaf(y.w, W[15], a3);
  return (a0 + a1) + (a2 + a3);
}

constexpr int TSTEPS = 256;

// wave = 1 batch element; lanes 0-31 = net r1 duties, lanes 32-63 = net r2.
// block = 64 (1 wave), grid = 4096. launch_bounds(64,4) -> 16 blocks/CU exact.
__global__ __launch_bounds__(64, 4) void reac_kernel(
    const float* __restrict__ useq,   // [B][T] f32
    const float* __restrict__ xz0,    // [B][26] f32
    const float* __restrict__ r1W0, const float* __restrict__ r1b0,
    const float* __restrict__ r1W1, const float* __restrict__ r1b1,
    const float* __restrict__ r1W2, const float* __restrict__ r1b2,
    const float* __restrict__ r2W0, const float* __restrict__ r2b0,
    const float* __restrict__ r2W1, const float* __restrict__ r2b1,
    const float* __restrict__ r2W2, const float* __restrict__ r2b2,
    const float* __restrict__ r3W0, const float* __restrict__ r3b0,
    const float* __restrict__ r3W1, const float* __restrict__ r3b1,
    const float* __restrict__ r3W2, const float* __restrict__ r3b2,
    float2* __restrict__ out)         // [B][T] -> (x0,x1) f32
{
  const int lane = threadIdx.x;
  const int j = lane & 31;
  const bool hi = lane >= 32;      // high half = r2 net
  const int b = blockIdx.x;

  // ---- per-half net weights (column j) ----
  const float* W0p = hi ? r2W0 : r1W0;
  const float* B0p = hi ? r2b0 : r1b0;
  const float* W1p = hi ? r2W1 : r1W1;
  const float* B1p = hi ? r2b1 : r1b1;
  const float* W2p = hi ? r2W2 : r1W2;
  const float* B2p = hi ? r2b2 : r1b2;
  float w0 = W0p[j], b0 = B0p[j], b1 = B1p[j], w2 = W2p[j], b2 = B2p[0];
  float sc = hi ? 0.2f : 0.3f;     // ystd scale for the net's output

  float W1[32];
#pragma unroll
  for (int k = 0; k < 32; ++k) W1[k] = W1p[k * 32 + j];

  // ---- r3 weights: W0C full, W1C k-half ----
  float W0C[24];
#pragma unroll
  for (int m = 0; m < 24; ++m) W0C[m] = r3W0[m * 32 + j];
  const int kbase = hi ? 16 : 0;
  float W1C[16];
#pragma unroll
  for (int k = 0; k < 16; ++k) W1C[k] = r3W1[(kbase + k) * 32 + j];
  float b0C = r3b0[j], b1C = r3b1[j], w2C = r3W2[j], b2C = r3b2[0];

  __shared__ __align__(16) float zs[24];      // z state
  __shared__ __align__(16) float zb[16];      // z4 prefix [xpseq[2:], x]
  __shared__ __align__(16) float h12[2][32];  // r1 / r2 hidden broadcast
  __shared__ __align__(16) float hR3[3][32];  // r3 hidden (z, z23, z4)

  float x0 = xz0[b * 26 + 0];
  float x1 = xz0[b * 26 + 1];
  if (!hi && j < 24) zs[j] = xz0[b * 26 + 2 + j];
  LDSBAR();

  // RK stage: low half runs r1(sx), high half runs r2(sy); both emit kx,ky.
  auto stage = [&](float sxv, float syv, float rc, float Caf,
                   float& kx, float& ky) {
    float s = hi ? syv : sxv;
    float h = tanh_fast(fmaf(s, w0, b0));
    LDSBAR();                      // prior readers of h12 done
    h12[hi][j] = h;
    LDSBAR();
    float a = dot32(&h12[hi][0], W1, b1);
    float r = (rsum32(tanh_fast(a) * w2) + b2) * sc;
    float rp = __shfl_xor(r, 32);
    float ra = hi ? rp : r;        // r1 result
    float rb = hi ? r : rp;        // r2 result
    float Ca = fmaf(sxv, 0.3f, 0.5f);
    float Cb = fmaf(syv, 0.2f, 0.5f);
    float dCa = 0.1f * (Caf - Ca) - ra;
    float dCb = fmaf(-0.1f, Cb, ra - 3.0f * rb + rc);
    kx = dCa * (1.0f / 0.3f);
    ky = dCb * (1.0f / 0.2f);
  };

  float u = useq[b * TSTEPS];

  for (int t = 0; t < TSTEPS; ++t) {
    int tn = (t < TSTEPS - 1) ? (t + 1) : t;
    float u_nxt = useq[b * TSTEPS + tn];   // prefetch, consumed next iter
    float Caf = fmaf(u, 0.5f, 1.0f);

    if (lane == 0) out[b * TSTEPS + t] = make_float2(x0, x1);

    // z4 prefix into zb
    if (!hi && j < 16) {
      zb[j] = (j < 14) ? zs[j + 2] : ((j == 14) ? x0 : x1);
    }
    LDSBAR();

    // ---- r3 x3: low computes A1 (on z), high computes A4 (on z4) ----
    const float4* zp = (const float4*)(hi ? &zb[0] : &zs[0]);
    float4 z0 = zp[0], z1 = zp[1], z2 = zp[2], z3 = zp[3];
    const float4* up = (const float4*)&zs[16];     // shared upseq tail
    float4 u0 = up[0], u1 = up[1];
    float A = b0C +
        ((dot4(z0, W0C) + dot4(z1, W0C + 4)) +
         (dot4(z2, W0C + 8) + dot4(z3, W0C + 12))) +
        (dot4(u0, W0C + 16) + dot4(u1, W0C + 20));
    float Ap = __shfl_xor(A, 32);                  // partner's A
    float tA = tanh_fast(A);
    if (!hi) {
      hR3[0][j] = tA;                              // h(z)
      hR3[1][j] = tanh_fast(0.5f * (A + Ap));      // h(z23), exact linearity
    } else {
      hR3[2][j] = tA;                              // h(z4)
    }
    LDSBAR();
    float p0 = pdot16(&hR3[0][kbase], W1C);
    float p1 = pdot16(&hR3[1][kbase], W1C);
    float p2 = pdot16(&hR3[2][kbase], W1C);
    float o0 = p0 + __shfl_xor(p0, 32) + b1C;
    float o1 = p1 + __shfl_xor(p1, 32) + b1C;
    float o2 = p2 + __shfl_xor(p2, 32) + b1C;
    float rc1  = (rsum32(tanh_fast(o0) * w2C) + b2C) * 0.2f;
    float rc23 = (rsum32(tanh_fast(o1) * w2C) + b2C) * 0.2f;
    float rc4  = (rsum32(tanh_fast(o2) * w2C) + b2C) * 0.2f;

    // ---- RK stages ----
    float kx1, ky1, kx2, ky2, kx3, ky3, kx4, ky4;
    stage(x0, x1, rc1, Caf, kx1, ky1);
    stage(fmaf(kx1, 0.5f, x0), fmaf(ky1, 0.5f, x1), rc23, Caf, kx2, ky2);
    stage(fmaf(kx2, 0.5f, x0), fmaf(ky2, 0.5f, x1), rc23, Caf, kx3, ky3);
    stage(x0 + kx3, x1 + ky3, rc4, Caf, kx4, ky4);

    // ---- state update: zplus = [xpseq[2:], x, upseq[1:], u] ----
    float znew = 0.0f;
    bool updz = (!hi) && (j < 24);
    if (updz) znew = (j < 16) ? zb[j] : ((j < 23) ? zs[j + 1] : u);
    LDSBAR();                      // all reads of zs/zb complete
    if (updz) zs[j] = znew;
    x0 += (kx1 + 2.0f * (kx2 + kx3) + kx4) * (1.0f / 6.0f);
    x1 += (ky1 + 2.0f * (ky2 + ky3) + ky4) * (1.0f / 6.0f);
    u = u_nxt;
    LDSBAR();                      // zs visible to next iteration's readers
  }
}

extern "C" void kernel_launch(void* const* d_in, const int* in_sizes, int n_in,
                              void* d_out, int out_size, void* d_ws, size_t ws_size,
                              hipStream_t stream) {
  const float* p[20];
  for (int i = 0; i < 20; ++i) p[i] = (const float*)d_in[i];
  reac_kernel<<<dim3(4096), dim3(64), 0, stream>>>(
      p[0], p[1], p[2], p[3], p[4], p[5], p[6], p[7], p[8], p[9], p[10],
      p[11], p[12], p[13], p[14], p[15], p[16], p[17], p[18], p[19],
      (float2*)d_out);
}